// Round 5
// baseline (559.383 us; speedup 1.0000x reference)
//
#include <hip/hip_runtime.h>

#define B_ 8
#define T_ 2048
#define E_ 256
#define H_ 8
#define DH_ 32
#define SCALING_ 0.17677669529663687f  // 1/sqrt(32)

typedef short bf16x8 __attribute__((ext_vector_type(8)));   // 8 bf16 in 4 VGPRs
typedef short bf16x4 __attribute__((ext_vector_type(4)));   // 4 bf16 in 2 VGPRs
typedef float floatx4 __attribute__((ext_vector_type(4)));

__device__ __forceinline__ unsigned short f2bf(float f) {
    union { float f; unsigned u; } v; v.f = f;
    unsigned r = v.u + 0x7FFFu + ((v.u >> 16) & 1u);   // RNE
    return (unsigned short)(r >> 16);
}

// round-half-up bf16 (2 VALU) — for softmax probs
__device__ __forceinline__ unsigned short f2bfru(float f) {
    union { float f; unsigned u; } v; v.f = f;
    return (unsigned short)((v.u + 0x8000u) >> 16);
}

__device__ __forceinline__ unsigned pk2(float a, float b) {
    return (unsigned)f2bfru(a) | ((unsigned)f2bfru(b) << 16);
}

__device__ __forceinline__ bf16x8 pack8(float4 a, float4 b) {
    bf16x8 o;
    o[0] = (short)f2bf(a.x); o[1] = (short)f2bf(a.y);
    o[2] = (short)f2bf(a.z); o[3] = (short)f2bf(a.w);
    o[4] = (short)f2bf(b.x); o[5] = (short)f2bf(b.y);
    o[6] = (short)f2bf(b.z); o[7] = (short)f2bf(b.w);
    return o;
}

// K=16 bf16 MFMA: P (QK C/D layout) feeds B operand directly — no LDS.
__device__ __forceinline__ floatx4 mfma16x16(bf16x4 a, bf16x4 b, floatx4 c) {
#if __has_builtin(__builtin_amdgcn_mfma_f32_16x16x16bf16_1k)
    return __builtin_amdgcn_mfma_f32_16x16x16bf16_1k(a, b, c, 0, 0, 0);
#else
    floatx4 d;
    asm("v_mfma_f32_16x16x16_bf16 %0, %1, %2, %3" : "=v"(d) : "v"(a), "v"(b), "v"(c));
    return d;
#endif
}

// ---------------------------------------------------------------------------
// Kernel 0: fused weight prepack (blocks 0..127) + mask nonzero check.
// ---------------------------------------------------------------------------
__global__ __launch_bounds__(256) void prep_maskchk_kernel(
    const float* __restrict__ Wq, const float* __restrict__ Wk,
    const float* __restrict__ Wv, const float* __restrict__ Wo,
    unsigned short* __restrict__ Wpack,
    const int* __restrict__ mask, int* __restrict__ mask_nz) {
    if (blockIdx.x < 128) {
        int idx = blockIdx.x * 256 + threadIdx.x;   // 32768 threads
        int m = idx >> 13;                           // matrix id 0..3
        int e = (idx & 8191) * 8;
        const float* W = (m == 0) ? Wq : (m == 1) ? Wk : (m == 2) ? Wv : Wo;
        float4 a = ((const float4*)(W + e))[0];
        float4 b = ((const float4*)(W + e))[1];
        *(bf16x8*)(Wpack + (size_t)m * 65536 + e) = pack8(a, b);
    }
    const size_t n4 = (size_t)B_ * T_ * T_ / 4;   // int4 count = 8,388,608
    size_t gid = (size_t)blockIdx.x * 256 + threadIdx.x;
    int acc = 0;
    for (size_t i = gid; i < n4; i += (size_t)2048 * 256) {
        int4 v = ((const int4*)mask)[i];
        acc |= v.x | v.y | v.z | v.w;
    }
    if (__builtin_amdgcn_ballot_w64(acc != 0)) {
        if ((threadIdx.x & 63) == 0) atomicOr(mask_nz, 1);
    }
}

// ---------------------------------------------------------------------------
// Kernel 1: QKV projection (bf16 weights). Grid = 3 x 512 blocks.
// ---------------------------------------------------------------------------
__global__ __launch_bounds__(256, 4) void qkv_kernel(
    const float* __restrict__ hs, const float* __restrict__ oq,
    const unsigned short* __restrict__ Wpack,
    const float* __restrict__ bq, const float* __restrict__ bk,
    const float* __restrict__ bv,
    unsigned short* __restrict__ Qw, unsigned short* __restrict__ Kw,
    unsigned short* __restrict__ Vtw) {
    __shared__ __align__(16) unsigned short sX[32][264];
    const int mat = blockIdx.x >> 9;          // 0=Q, 1=K, 2=V
    const int mbase = (blockIdx.x & 511) * 32;
    const int b = mbase >> 11, tbase = mbase & 2047;
    const int tid = threadIdx.x;

#pragma unroll
    for (int i = 0; i < 8; ++i) {
        int idx = tid + i * 256;
        int row = idx >> 6, c4 = idx & 63;
        float4 hv = ((const float4*)(hs + (size_t)(mbase + row) * E_))[c4];
        if (mat < 2) {
            float4 ov = ((const float4*)(oq + (size_t)(mbase + row) * E_))[c4];
            hv.x += ov.x; hv.y += ov.y; hv.z += ov.z; hv.w += ov.w;
        }
        ushort4 pb;
        pb.x = f2bf(hv.x); pb.y = f2bf(hv.y); pb.z = f2bf(hv.z); pb.w = f2bf(hv.w);
        *(ushort4*)&sX[row][c4 * 4] = pb;
    }
    __syncthreads();

    const int wave = tid >> 6, lane = tid & 63;
    const int quad = lane >> 4, m16 = lane & 15;
    const unsigned short* W = Wpack + (size_t)mat * 65536;

    bf16x8 xf[2][8];
#pragma unroll
    for (int hgrp = 0; hgrp < 2; ++hgrp)
#pragma unroll
        for (int kc = 0; kc < 8; ++kc)
            xf[hgrp][kc] = *(const bf16x8*)&sX[hgrp * 16 + m16][kc * 32 + quad * 8];

    if (mat < 2) {
        const float* bias = (mat == 0) ? bq : bk;
        unsigned short* Out = (mat == 0) ? Qw : Kw;
#pragma unroll
        for (int i = 0; i < 4; ++i) {
            int nt = wave * 4 + i;
            int ecol = nt * 16 + m16;
            const unsigned short* wrow = W + (size_t)ecol * E_;
            floatx4 acc0 = {0.f, 0.f, 0.f, 0.f};
            floatx4 acc1 = {0.f, 0.f, 0.f, 0.f};
#pragma unroll
            for (int kc = 0; kc < 8; ++kc) {
                bf16x8 bf = *(const bf16x8*)(wrow + kc * 32 + quad * 8);
                acc0 = __builtin_amdgcn_mfma_f32_16x16x32_bf16(xf[0][kc], bf, acc0, 0, 0, 0);
                acc1 = __builtin_amdgcn_mfma_f32_16x16x32_bf16(xf[1][kc], bf, acc1, 0, 0, 0);
            }
            float bs = bias[ecol];
            int h = ecol >> 5, dh = ecol & 31;
            size_t base0 = (((size_t)b * H_ + h) * T_ + (tbase + quad * 4)) * DH_ + dh;
            size_t base1 = base0 + (size_t)16 * DH_;
#pragma unroll
            for (int r = 0; r < 4; ++r) {
                float v0 = acc0[r] + bs, v1 = acc1[r] + bs;
                if (mat == 0) { v0 *= SCALING_; v1 *= SCALING_; }
                Out[base0 + (size_t)r * DH_] = f2bf(v0);
                Out[base1 + (size_t)r * DH_] = f2bf(v1);
            }
        }
    } else {
#pragma unroll
        for (int i = 0; i < 4; ++i) {
            int et = wave * 4 + i;
            int erow = et * 16 + m16;
            const unsigned short* wrow = W + (size_t)erow * E_;
            floatx4 acc0 = {0.f, 0.f, 0.f, 0.f};
            floatx4 acc1 = {0.f, 0.f, 0.f, 0.f};
#pragma unroll
            for (int kc = 0; kc < 8; ++kc) {
                bf16x8 wf = *(const bf16x8*)(wrow + kc * 32 + quad * 8);
                acc0 = __builtin_amdgcn_mfma_f32_16x16x32_bf16(wf, xf[0][kc], acc0, 0, 0, 0);
                acc1 = __builtin_amdgcn_mfma_f32_16x16x32_bf16(wf, xf[1][kc], acc1, 0, 0, 0);
            }
            int t0 = tbase + m16, t1 = t0 + 16;
#pragma unroll
            for (int r = 0; r < 4; ++r) {
                int ev = et * 16 + quad * 4 + r;
                int h = ev >> 5, dh = ev & 31;
                size_t vb = (((size_t)b * H_ + h) * DH_ + dh) * T_;
                Vtw[vb + t0] = f2bf(acc0[r] + bv[ev]);
                Vtw[vb + t1] = f2bf(acc1[r] + bv[ev]);
            }
        }
    }
}

// ---------------------------------------------------------------------------
// Kernel 2: flash attention, S^T form, REGISTER-ONLY P path (no LDS at all).
// QK^T: mfma_16x16x32(K,Q) -> D[key][q]; its C/D layout (lane: q=lane&15,
// keys=quad*4+r) IS the B-operand layout of mfma_f32_16x16x16_bf16, so PV
// consumes P straight from registers. Per 128-key tile: 8 QK MFMA (K=32) +
// 16 PV MFMA (K=16). 1-deep K prefetch; V loaded early each half-tile.
// Fast path (mask==0): plain exp (no max), per-lane scalar l. Slow path:
// online softmax with float4 mask loads.
// ---------------------------------------------------------------------------
__global__ __launch_bounds__(256, 4) void attn_kernel(
    const unsigned short* __restrict__ Qw, const unsigned short* __restrict__ Kw,
    const unsigned short* __restrict__ Vtw, const float* __restrict__ mask,
    const int* __restrict__ mask_nz, unsigned short* __restrict__ attnw) {
    const int tid = threadIdx.x;
    const int wave = tid >> 6, lane = tid & 63;
    const int quad = lane >> 4, m16 = lane & 15;
    const int bh = blockIdx.x & 63, qt = blockIdx.x >> 6;   // bh%8==h -> XCD
    const int b = bh >> 3, h = bh & 7;
    const int q0 = qt * 64 + wave * 16;
    const int mnz = *mask_nz;

    // Q fragment (B operand of K=32 MFMA): B[n=q=lane&15][k=quad*8+j]
    bf16x8 qfrag = *(const bf16x8*)(Qw + ((size_t)bh * T_ + q0 + m16) * DH_ + quad * 8);
    const unsigned short* Kb = Kw + (size_t)bh * T_ * DH_;
    const unsigned short* Vb = Vtw + (size_t)bh * DH_ * T_;
    const float* Mb = mask + ((size_t)b * T_ + q0 + m16) * T_ + quad * 4;

    floatx4 O0 = {0.f, 0.f, 0.f, 0.f};   // O^T: dh = quad*4+r, q = m16
    floatx4 O1 = {0.f, 0.f, 0.f, 0.f};   // dh = 16+quad*4+r
    float mprev = -1e30f;                 // slow path only
    float lpart = 0.f;
    const floatx4 zero = {0.f, 0.f, 0.f, 0.f};

    // K fragment pointers: row (s + m16), 16B at offset quad*8
    // Prefetch tile 0's K fragments.
    bf16x8 kf[8];
#pragma unroll
    for (int c = 0; c < 8; ++c)
        kf[c] = *(const bf16x8*)(Kb + (size_t)(c * 16 + m16) * DH_ + quad * 8);

    for (int kt = 0; kt < 16; ++kt) {
        const int s0 = kt * 128;
        // process in two 64-key halves to bound live registers
#pragma unroll
        for (int hf = 0; hf < 2; ++hf) {
            const int cb = hf * 4;
            // V fragments for this half (independent -> latency hidden by QK/exp)
            bf16x4 vf0[4], vf1[4];
#pragma unroll
            for (int c = 0; c < 4; ++c) {
                int ko = s0 + (cb + c) * 16 + quad * 4;
                vf0[c] = *(const bf16x4*)(Vb + (size_t)m16 * T_ + ko);
                vf1[c] = *(const bf16x4*)(Vb + (size_t)(16 + m16) * T_ + ko);
            }
            floatx4 sc[4];
#pragma unroll
            for (int c = 0; c < 4; ++c)
                sc[c] = __builtin_amdgcn_mfma_f32_16x16x32_bf16(kf[cb + c], qfrag, zero, 0, 0, 0);
            // prefetch next tile's K for this half's slots
            if (kt < 15) {
#pragma unroll
                for (int c = 0; c < 4; ++c)
                    kf[cb + c] = *(const bf16x8*)(
                        Kb + (size_t)(s0 + 128 + (cb + c) * 16 + m16) * DH_ + quad * 8);
            }
            bf16x4 pf[4];
            if (!mnz) {
                // FAST PATH: no max, no rescale, no shuffles.
#pragma unroll
                for (int c = 0; c < 4; ++c) {
                    float p0 = __expf(sc[c][0]), p1 = __expf(sc[c][1]);
                    float p2 = __expf(sc[c][2]), p3 = __expf(sc[c][3]);
                    lpart += (p0 + p1) + (p2 + p3);
                    union { uint2 u; bf16x4 v; } w;
                    w.u.x = pk2(p0, p1); w.u.y = pk2(p2, p3);
                    pf[c] = w.v;
                }
            } else {
                // SLOW PATH: online softmax; float4 mask loads.
#pragma unroll
                for (int c = 0; c < 4; ++c) {
                    float4 mv = *(const float4*)(Mb + s0 + (cb + c) * 16);
                    sc[c][0] += mv.x; sc[c][1] += mv.y; sc[c][2] += mv.z; sc[c][3] += mv.w;
                }
                float mloc = -1e30f;
#pragma unroll
                for (int c = 0; c < 4; ++c)
                    mloc = fmaxf(fmaxf(fmaxf(sc[c][0], sc[c][1]), fmaxf(sc[c][2], sc[c][3])), mloc);
                mloc = fmaxf(mloc, __shfl_xor(mloc, 16, 64));
                mloc = fmaxf(mloc, __shfl_xor(mloc, 32, 64));
                float mn = fmaxf(mprev, mloc);
                float alpha = __expf(mprev - mn);
                mprev = mn;
                lpart *= alpha;
#pragma unroll
                for (int r = 0; r < 4; ++r) { O0[r] *= alpha; O1[r] *= alpha; }
#pragma unroll
                for (int c = 0; c < 4; ++c) {
                    float p0 = __expf(sc[c][0] - mn), p1 = __expf(sc[c][1] - mn);
                    float p2 = __expf(sc[c][2] - mn), p3 = __expf(sc[c][3] - mn);
                    lpart += (p0 + p1) + (p2 + p3);
                    union { uint2 u; bf16x4 v; } w;
                    w.u.x = pk2(p0, p1); w.u.y = pk2(p2, p3);
                    pf[c] = w.v;
                }
            }
            // PV: O^T[dh][q] += V^T[dh][key] · P[key][q], K=16, P from registers
#pragma unroll
            for (int c = 0; c < 4; ++c) {
                O0 = mfma16x16(vf0[c], pf[c], O0);
                O1 = mfma16x16(vf1[c], pf[c], O1);
            }
        }
    }
    // l reduction across the 4 quads holding this q's keys
    lpart += __shfl_xor(lpart, 16, 64);
    lpart += __shfl_xor(lpart, 32, 64);
    float inv = 1.0f / lpart;
    // store: row = b*T + q0 + m16 (q), cols h*32 + quad*4(+16); 2 b64 stores
    size_t ob = ((size_t)b * T_ + q0 + m16) * E_ + h * DH_ + quad * 4;
    ushort4 s0v, s1v;
    s0v.x = f2bf(O0[0] * inv); s0v.y = f2bf(O0[1] * inv);
    s0v.z = f2bf(O0[2] * inv); s0v.w = f2bf(O0[3] * inv);
    s1v.x = f2bf(O1[0] * inv); s1v.y = f2bf(O1[1] * inv);
    s1v.z = f2bf(O1[2] * inv); s1v.w = f2bf(O1[3] * inv);
    *(ushort4*)(attnw + ob) = s0v;
    *(ushort4*)(attnw + ob + 16) = s1v;
}

// ---------------------------------------------------------------------------
// Kernel 3: output projection: out = attn @ Wo^T + bo  (fp32 out, bf16 weights)
// ---------------------------------------------------------------------------
__global__ __launch_bounds__(256, 4) void oproj_kernel(
    const unsigned short* __restrict__ attnw, const unsigned short* __restrict__ Wob,
    const float* __restrict__ bo, float* __restrict__ out) {
    __shared__ __align__(16) unsigned short sA[16][264];
    const int tid = threadIdx.x;
    const int mbase = blockIdx.x * 16;
#pragma unroll
    for (int i = 0; i < 4; ++i) {
        int idx = tid + i * 256;
        int row = idx >> 6, c4 = idx & 63;
        const ushort4 a = ((const ushort4*)(attnw + (size_t)(mbase + row) * E_))[c4];
        *(ushort4*)&sA[row][c4 * 4] = a;
    }
    __syncthreads();
    const int wave = tid >> 6, lane = tid & 63;
    const int quad = lane >> 4, m16 = lane & 15;

    bf16x8 af[8];
#pragma unroll
    for (int kc = 0; kc < 8; ++kc)
        af[kc] = *(const bf16x8*)&sA[m16][kc * 32 + quad * 8];

#pragma unroll
    for (int i = 0; i < 4; ++i) {
        int nt = wave * 4 + i;
        int ecol = nt * 16 + m16;
        const unsigned short* wrow = Wob + (size_t)ecol * E_;
        floatx4 acc = {0.f, 0.f, 0.f, 0.f};
#pragma unroll
        for (int kc = 0; kc < 8; ++kc) {
            bf16x8 bf = *(const bf16x8*)(wrow + kc * 32 + quad * 8);
            acc = __builtin_amdgcn_mfma_f32_16x16x32_bf16(af[kc], bf, acc, 0, 0, 0);
        }
        float bias = bo[ecol];
        size_t base = (size_t)(mbase + quad * 4) * E_ + ecol;
#pragma unroll
        for (int r = 0; r < 4; ++r)
            out[base + (size_t)r * E_] = acc[r] + bias;
    }
}

extern "C" void kernel_launch(void* const* d_in, const int* in_sizes, int n_in,
                              void* d_out, int out_size, void* d_ws, size_t ws_size,
                              hipStream_t stream) {
    const float* hs   = (const float*)d_in[0];
    const float* oq   = (const float*)d_in[1];
    const float* mask = (const float*)d_in[2];
    const float* Wq   = (const float*)d_in[3];
    const float* bq   = (const float*)d_in[4];
    const float* Wk   = (const float*)d_in[5];
    const float* bk   = (const float*)d_in[6];
    const float* Wv   = (const float*)d_in[7];
    const float* bv   = (const float*)d_in[8];
    const float* Wo   = (const float*)d_in[9];
    const float* bo   = (const float*)d_in[10];
    float* out = (float*)d_out;

    const size_t nBHTD = (size_t)B_ * H_ * T_ * DH_;   // 4,194,304 elems
    unsigned short* Qw    = (unsigned short*)d_ws;
    unsigned short* Kw    = Qw + nBHTD;
    unsigned short* Vtw   = Kw + nBHTD;
    unsigned short* attnw = Vtw + nBHTD;               // 4 x 8 MB
    unsigned short* Wpack = attnw + nBHTD;             // + 512 KB
    int* mask_nz = (int*)(Wpack + 4 * 65536);

    hipMemsetAsync(mask_nz, 0, sizeof(int), stream);
    prep_maskchk_kernel<<<2048, 256, 0, stream>>>(Wq, Wk, Wv, Wo, Wpack,
                                                  (const int*)mask, mask_nz);
    qkv_kernel<<<3 * 512, 256, 0, stream>>>(hs, oq, Wpack, bq, bk, bv, Qw, Kw, Vtw);
    attn_kernel<<<B_ * H_ * (T_ / 64), 256, 0, stream>>>(Qw, Kw, Vtw, mask, mask_nz, attnw);
    oproj_kernel<<<(B_ * T_) / 16, 256, 0, stream>>>(attnw, Wpack + 3 * 65536, bo, out);
}

// Round 6
// 380.634 us; speedup vs baseline: 1.4696x; 1.4696x over previous
//
#include <hip/hip_runtime.h>

#define B_ 8
#define T_ 2048
#define E_ 256
#define H_ 8
#define DH_ 32
#define SCALING_ 0.17677669529663687f  // 1/sqrt(32)

typedef short bf16x8 __attribute__((ext_vector_type(8)));   // 8 bf16 in 4 VGPRs
typedef float floatx4 __attribute__((ext_vector_type(4)));

__device__ __forceinline__ unsigned short f2bf(float f) {
    union { float f; unsigned u; } v; v.f = f;
    unsigned r = v.u + 0x7FFFu + ((v.u >> 16) & 1u);   // RNE
    return (unsigned short)(r >> 16);
}

// round-half-up bf16 (2 VALU) — for softmax probs
__device__ __forceinline__ unsigned short f2bfru(float f) {
    union { float f; unsigned u; } v; v.f = f;
    return (unsigned short)((v.u + 0x8000u) >> 16);
}

__device__ __forceinline__ unsigned pk2(float a, float b) {
    return (unsigned)f2bfru(a) | ((unsigned)f2bfru(b) << 16);
}

__device__ __forceinline__ bf16x8 pack8(float4 a, float4 b) {
    bf16x8 o;
    o[0] = (short)f2bf(a.x); o[1] = (short)f2bf(a.y);
    o[2] = (short)f2bf(a.z); o[3] = (short)f2bf(a.w);
    o[4] = (short)f2bf(b.x); o[5] = (short)f2bf(b.y);
    o[6] = (short)f2bf(b.z); o[7] = (short)f2bf(b.w);
    return o;
}

// ---------------------------------------------------------------------------
// Kernel 0: fused weight prepack (blocks 0..127) + mask nonzero check.
// ---------------------------------------------------------------------------
__global__ __launch_bounds__(256) void prep_maskchk_kernel(
    const float* __restrict__ Wq, const float* __restrict__ Wk,
    const float* __restrict__ Wv, const float* __restrict__ Wo,
    unsigned short* __restrict__ Wpack,
    const int* __restrict__ mask, int* __restrict__ mask_nz) {
    if (blockIdx.x < 128) {
        int idx = blockIdx.x * 256 + threadIdx.x;   // 32768 threads
        int m = idx >> 13;                           // matrix id 0..3
        int e = (idx & 8191) * 8;
        const float* W = (m == 0) ? Wq : (m == 1) ? Wk : (m == 2) ? Wv : Wo;
        float4 a = ((const float4*)(W + e))[0];
        float4 b = ((const float4*)(W + e))[1];
        *(bf16x8*)(Wpack + (size_t)m * 65536 + e) = pack8(a, b);
    }
    const size_t n4 = (size_t)B_ * T_ * T_ / 4;   // int4 count = 8,388,608
    size_t gid = (size_t)blockIdx.x * 256 + threadIdx.x;
    int acc = 0;
    for (size_t i = gid; i < n4; i += (size_t)2048 * 256) {
        int4 v = ((const int4*)mask)[i];
        acc |= v.x | v.y | v.z | v.w;
    }
    if (__builtin_amdgcn_ballot_w64(acc != 0)) {
        if ((threadIdx.x & 63) == 0) atomicOr(mask_nz, 1);
    }
}

// ---------------------------------------------------------------------------
// Kernel 1: QKV projection (bf16 weights). Grid = 3 x 512 blocks.
// ---------------------------------------------------------------------------
__global__ __launch_bounds__(256, 4) void qkv_kernel(
    const float* __restrict__ hs, const float* __restrict__ oq,
    const unsigned short* __restrict__ Wpack,
    const float* __restrict__ bq, const float* __restrict__ bk,
    const float* __restrict__ bv,
    unsigned short* __restrict__ Qw, unsigned short* __restrict__ Kw,
    unsigned short* __restrict__ Vtw) {
    __shared__ __align__(16) unsigned short sX[32][264];
    const int mat = blockIdx.x >> 9;          // 0=Q, 1=K, 2=V
    const int mbase = (blockIdx.x & 511) * 32;
    const int b = mbase >> 11, tbase = mbase & 2047;
    const int tid = threadIdx.x;

#pragma unroll
    for (int i = 0; i < 8; ++i) {
        int idx = tid + i * 256;
        int row = idx >> 6, c4 = idx & 63;
        float4 hv = ((const float4*)(hs + (size_t)(mbase + row) * E_))[c4];
        if (mat < 2) {
            float4 ov = ((const float4*)(oq + (size_t)(mbase + row) * E_))[c4];
            hv.x += ov.x; hv.y += ov.y; hv.z += ov.z; hv.w += ov.w;
        }
        ushort4 pb;
        pb.x = f2bf(hv.x); pb.y = f2bf(hv.y); pb.z = f2bf(hv.z); pb.w = f2bf(hv.w);
        *(ushort4*)&sX[row][c4 * 4] = pb;
    }
    __syncthreads();

    const int wave = tid >> 6, lane = tid & 63;
    const int quad = lane >> 4, m16 = lane & 15;
    const unsigned short* W = Wpack + (size_t)mat * 65536;

    bf16x8 xf[2][8];
#pragma unroll
    for (int hgrp = 0; hgrp < 2; ++hgrp)
#pragma unroll
        for (int kc = 0; kc < 8; ++kc)
            xf[hgrp][kc] = *(const bf16x8*)&sX[hgrp * 16 + m16][kc * 32 + quad * 8];

    if (mat < 2) {
        const float* bias = (mat == 0) ? bq : bk;
        unsigned short* Out = (mat == 0) ? Qw : Kw;
#pragma unroll
        for (int i = 0; i < 4; ++i) {
            int nt = wave * 4 + i;
            int ecol = nt * 16 + m16;
            const unsigned short* wrow = W + (size_t)ecol * E_;
            floatx4 acc0 = {0.f, 0.f, 0.f, 0.f};
            floatx4 acc1 = {0.f, 0.f, 0.f, 0.f};
#pragma unroll
            for (int kc = 0; kc < 8; ++kc) {
                bf16x8 bf = *(const bf16x8*)(wrow + kc * 32 + quad * 8);
                acc0 = __builtin_amdgcn_mfma_f32_16x16x32_bf16(xf[0][kc], bf, acc0, 0, 0, 0);
                acc1 = __builtin_amdgcn_mfma_f32_16x16x32_bf16(xf[1][kc], bf, acc1, 0, 0, 0);
            }
            float bs = bias[ecol];
            int h = ecol >> 5, dh = ecol & 31;
            size_t base0 = (((size_t)b * H_ + h) * T_ + (tbase + quad * 4)) * DH_ + dh;
            size_t base1 = base0 + (size_t)16 * DH_;
#pragma unroll
            for (int r = 0; r < 4; ++r) {
                float v0 = acc0[r] + bs, v1 = acc1[r] + bs;
                if (mat == 0) { v0 *= SCALING_; v1 *= SCALING_; }
                Out[base0 + (size_t)r * DH_] = f2bf(v0);
                Out[base1 + (size_t)r * DH_] = f2bf(v1);
            }
        }
    } else {
#pragma unroll
        for (int i = 0; i < 4; ++i) {
            int et = wave * 4 + i;
            int erow = et * 16 + m16;
            const unsigned short* wrow = W + (size_t)erow * E_;
            floatx4 acc0 = {0.f, 0.f, 0.f, 0.f};
            floatx4 acc1 = {0.f, 0.f, 0.f, 0.f};
#pragma unroll
            for (int kc = 0; kc < 8; ++kc) {
                bf16x8 wf = *(const bf16x8*)(wrow + kc * 32 + quad * 8);
                acc0 = __builtin_amdgcn_mfma_f32_16x16x32_bf16(wf, xf[0][kc], acc0, 0, 0, 0);
                acc1 = __builtin_amdgcn_mfma_f32_16x16x32_bf16(wf, xf[1][kc], acc1, 0, 0, 0);
            }
            int t0 = tbase + m16, t1 = t0 + 16;
#pragma unroll
            for (int r = 0; r < 4; ++r) {
                int ev = et * 16 + quad * 4 + r;
                int h = ev >> 5, dh = ev & 31;
                size_t vb = (((size_t)b * H_ + h) * DH_ + dh) * T_;
                Vtw[vb + t0] = f2bf(acc0[r] + bv[ev]);
                Vtw[vb + t1] = f2bf(acc1[r] + bv[ev]);
            }
        }
    }
}

// ---------------------------------------------------------------------------
// Kernel 2: flash attention, S^T form, TWO independent q-streams per wave.
// Each wave owns 32 q-rows (streams A: q0..q0+15, B: q0+16..q0+31); K and V
// fragment loads are shared by both streams (halves VMEM per q-row) and every
// pipeline stage is two independent dependency chains (2x ILP vs R4).
// QK^T: mfma(K,Q) -> D[key][q]; P transits per-wave LDS (C->A layout, K=32
// PV MFMA — R5 showed the register-direct K=16 path is slower). No barriers.
// Fast path (mask==0): plain exp, per-lane scalar l. Slow path: online
// softmax per stream, float4 mask loads. Grid = B*H*(T/128) = 1024 blocks.
// ---------------------------------------------------------------------------
__global__ __launch_bounds__(256, 3) void attn_kernel(
    const unsigned short* __restrict__ Qw, const unsigned short* __restrict__ Kw,
    const unsigned short* __restrict__ Vtw, const float* __restrict__ mask,
    const int* __restrict__ mask_nz, unsigned short* __restrict__ attnw) {
    __shared__ __align__(16) unsigned short sPT[4][2][16][136];  // [wave][stream][q][key]
    const int tid = threadIdx.x;
    const int wave = tid >> 6, lane = tid & 63;
    const int quad = lane >> 4, m16 = lane & 15;
    const int bh = blockIdx.x & 63, qt = blockIdx.x >> 6;   // bh%8==h -> XCD
    const int b = bh >> 3, h = bh & 7;
    const int qA = qt * 128 + wave * 32;    // stream A q-base
    const int qB = qA + 16;                 // stream B q-base
    const int mnz = *mask_nz;

    // Q fragments (B operand): B[n=q=lane&15][k=quad*8+j]
    bf16x8 qfragA = *(const bf16x8*)(Qw + ((size_t)bh * T_ + qA + m16) * DH_ + quad * 8);
    bf16x8 qfragB = *(const bf16x8*)(Qw + ((size_t)bh * T_ + qB + m16) * DH_ + quad * 8);
    const unsigned short* Kb = Kw + (size_t)bh * T_ * DH_;
    const unsigned short* Vb = Vtw + (size_t)bh * DH_ * T_;
    const float* MbA = mask + ((size_t)b * T_ + qA + m16) * T_ + quad * 4;
    const float* MbB = MbA + (size_t)16 * T_;

    floatx4 O0A = {0.f, 0.f, 0.f, 0.f}, O1A = {0.f, 0.f, 0.f, 0.f};
    floatx4 O0B = {0.f, 0.f, 0.f, 0.f}, O1B = {0.f, 0.f, 0.f, 0.f};
    float mprevA = -1e30f, mprevB = -1e30f;
    float lpartA = 0.f, lpartB = 0.f;
    const floatx4 zero = {0.f, 0.f, 0.f, 0.f};

    // 1-deep K prefetch (fragments shared by both streams)
    bf16x8 kf[8];
#pragma unroll
    for (int c = 0; c < 8; ++c)
        kf[c] = *(const bf16x8*)(Kb + (size_t)(c * 16 + m16) * DH_ + quad * 8);

    for (int kt = 0; kt < 16; ++kt) {
        const int s0 = kt * 128;
        // process in two 64-key halves to bound live registers
#pragma unroll
        for (int hf = 0; hf < 2; ++hf) {
            const int cb = hf * 4;
            floatx4 scA[4], scB[4];
#pragma unroll
            for (int c = 0; c < 4; ++c) {
                scA[c] = __builtin_amdgcn_mfma_f32_16x16x32_bf16(kf[cb + c], qfragA, zero, 0, 0, 0);
                scB[c] = __builtin_amdgcn_mfma_f32_16x16x32_bf16(kf[cb + c], qfragB, zero, 0, 0, 0);
            }
            // prefetch next tile's K for this half's slots
            if (kt < 15) {
#pragma unroll
                for (int c = 0; c < 4; ++c)
                    kf[cb + c] = *(const bf16x8*)(
                        Kb + (size_t)(s0 + 128 + (cb + c) * 16 + m16) * DH_ + quad * 8);
            }
            if (!mnz) {
                // FAST PATH: no max, no rescale, no shuffles; 2 indep exp chains.
#pragma unroll
                for (int c = 0; c < 4; ++c) {
                    float a0 = __expf(scA[c][0]), a1 = __expf(scA[c][1]);
                    float a2 = __expf(scA[c][2]), a3 = __expf(scA[c][3]);
                    float b0 = __expf(scB[c][0]), b1 = __expf(scB[c][1]);
                    float b2 = __expf(scB[c][2]), b3 = __expf(scB[c][3]);
                    lpartA += (a0 + a1) + (a2 + a3);
                    lpartB += (b0 + b1) + (b2 + b3);
                    uint2 wa = {pk2(a0, a1), pk2(a2, a3)};
                    uint2 wb = {pk2(b0, b1), pk2(b2, b3)};
                    *(uint2*)&sPT[wave][0][m16][(cb + c) * 16 + quad * 4] = wa;
                    *(uint2*)&sPT[wave][1][m16][(cb + c) * 16 + quad * 4] = wb;
                }
            } else {
                // SLOW PATH: online softmax per stream; float4 mask loads.
#pragma unroll
                for (int c = 0; c < 4; ++c) {
                    float4 ma = *(const float4*)(MbA + s0 + (cb + c) * 16);
                    float4 mb = *(const float4*)(MbB + s0 + (cb + c) * 16);
                    scA[c][0] += ma.x; scA[c][1] += ma.y; scA[c][2] += ma.z; scA[c][3] += ma.w;
                    scB[c][0] += mb.x; scB[c][1] += mb.y; scB[c][2] += mb.z; scB[c][3] += mb.w;
                }
                float mlA = -1e30f, mlB = -1e30f;
#pragma unroll
                for (int c = 0; c < 4; ++c) {
                    mlA = fmaxf(fmaxf(fmaxf(scA[c][0], scA[c][1]), fmaxf(scA[c][2], scA[c][3])), mlA);
                    mlB = fmaxf(fmaxf(fmaxf(scB[c][0], scB[c][1]), fmaxf(scB[c][2], scB[c][3])), mlB);
                }
                mlA = fmaxf(mlA, __shfl_xor(mlA, 16, 64));
                mlA = fmaxf(mlA, __shfl_xor(mlA, 32, 64));
                mlB = fmaxf(mlB, __shfl_xor(mlB, 16, 64));
                mlB = fmaxf(mlB, __shfl_xor(mlB, 32, 64));
                float mnA = fmaxf(mprevA, mlA), mnB = fmaxf(mprevB, mlB);
                float alA = __expf(mprevA - mnA), alB = __expf(mprevB - mnB);
                mprevA = mnA; mprevB = mnB;
                lpartA *= alA; lpartB *= alB;
#pragma unroll
                for (int r = 0; r < 4; ++r) {
                    O0A[r] *= alA; O1A[r] *= alA;
                    O0B[r] *= alB; O1B[r] *= alB;
                }
#pragma unroll
                for (int c = 0; c < 4; ++c) {
                    float a0 = __expf(scA[c][0] - mnA), a1 = __expf(scA[c][1] - mnA);
                    float a2 = __expf(scA[c][2] - mnA), a3 = __expf(scA[c][3] - mnA);
                    float b0 = __expf(scB[c][0] - mnB), b1 = __expf(scB[c][1] - mnB);
                    float b2 = __expf(scB[c][2] - mnB), b3 = __expf(scB[c][3] - mnB);
                    lpartA += (a0 + a1) + (a2 + a3);
                    lpartB += (b0 + b1) + (b2 + b3);
                    uint2 wa = {pk2(a0, a1), pk2(a2, a3)};
                    uint2 wb = {pk2(b0, b1), pk2(b2, b3)};
                    *(uint2*)&sPT[wave][0][m16][(cb + c) * 16 + quad * 4] = wa;
                    *(uint2*)&sPT[wave][1][m16][(cb + c) * 16 + quad * 4] = wb;
                }
            }
        }
        // PV: O^T[dh][q] += V^T[dh][key] · P[q][key]; V fragments shared by
        // both streams; 4 independent accumulator chains of depth 4.
#pragma unroll
        for (int sb = 0; sb < 4; ++sb) {
            bf16x8 pbA = *(const bf16x8*)&sPT[wave][0][m16][sb * 32 + quad * 8];
            bf16x8 pbB = *(const bf16x8*)&sPT[wave][1][m16][sb * 32 + quad * 8];
            bf16x8 v0 = *(const bf16x8*)(Vb + (size_t)m16 * T_ + s0 + sb * 32 + quad * 8);
            bf16x8 v1 = *(const bf16x8*)(Vb + (size_t)(16 + m16) * T_ + s0 + sb * 32 + quad * 8);
            O0A = __builtin_amdgcn_mfma_f32_16x16x32_bf16(v0, pbA, O0A, 0, 0, 0);
            O0B = __builtin_amdgcn_mfma_f32_16x16x32_bf16(v0, pbB, O0B, 0, 0, 0);
            O1A = __builtin_amdgcn_mfma_f32_16x16x32_bf16(v1, pbA, O1A, 0, 0, 0);
            O1B = __builtin_amdgcn_mfma_f32_16x16x32_bf16(v1, pbB, O1B, 0, 0, 0);
        }
    }
    // l reduction across the 4 quads holding each q's keys
    lpartA += __shfl_xor(lpartA, 16, 64);
    lpartA += __shfl_xor(lpartA, 32, 64);
    lpartB += __shfl_xor(lpartB, 16, 64);
    lpartB += __shfl_xor(lpartB, 32, 64);
    float invA = 1.0f / lpartA, invB = 1.0f / lpartB;
    size_t obA = ((size_t)b * T_ + qA + m16) * E_ + h * DH_ + quad * 4;
    size_t obB = ((size_t)b * T_ + qB + m16) * E_ + h * DH_ + quad * 4;
    ushort4 sv;
    sv.x = f2bf(O0A[0] * invA); sv.y = f2bf(O0A[1] * invA);
    sv.z = f2bf(O0A[2] * invA); sv.w = f2bf(O0A[3] * invA);
    *(ushort4*)(attnw + obA) = sv;
    sv.x = f2bf(O1A[0] * invA); sv.y = f2bf(O1A[1] * invA);
    sv.z = f2bf(O1A[2] * invA); sv.w = f2bf(O1A[3] * invA);
    *(ushort4*)(attnw + obA + 16) = sv;
    sv.x = f2bf(O0B[0] * invB); sv.y = f2bf(O0B[1] * invB);
    sv.z = f2bf(O0B[2] * invB); sv.w = f2bf(O0B[3] * invB);
    *(ushort4*)(attnw + obB) = sv;
    sv.x = f2bf(O1B[0] * invB); sv.y = f2bf(O1B[1] * invB);
    sv.z = f2bf(O1B[2] * invB); sv.w = f2bf(O1B[3] * invB);
    *(ushort4*)(attnw + obB + 16) = sv;
}

// ---------------------------------------------------------------------------
// Kernel 3: output projection: out = attn @ Wo^T + bo  (fp32 out, bf16 weights)
// ---------------------------------------------------------------------------
__global__ __launch_bounds__(256, 4) void oproj_kernel(
    const unsigned short* __restrict__ attnw, const unsigned short* __restrict__ Wob,
    const float* __restrict__ bo, float* __restrict__ out) {
    __shared__ __align__(16) unsigned short sA[16][264];
    const int tid = threadIdx.x;
    const int mbase = blockIdx.x * 16;
#pragma unroll
    for (int i = 0; i < 4; ++i) {
        int idx = tid + i * 256;
        int row = idx >> 6, c4 = idx & 63;
        const ushort4 a = ((const ushort4*)(attnw + (size_t)(mbase + row) * E_))[c4];
        *(ushort4*)&sA[row][c4 * 4] = a;
    }
    __syncthreads();
    const int wave = tid >> 6, lane = tid & 63;
    const int quad = lane >> 4, m16 = lane & 15;

    bf16x8 af[8];
#pragma unroll
    for (int kc = 0; kc < 8; ++kc)
        af[kc] = *(const bf16x8*)&sA[m16][kc * 32 + quad * 8];

#pragma unroll
    for (int i = 0; i < 4; ++i) {
        int nt = wave * 4 + i;
        int ecol = nt * 16 + m16;
        const unsigned short* wrow = Wob + (size_t)ecol * E_;
        floatx4 acc = {0.f, 0.f, 0.f, 0.f};
#pragma unroll
        for (int kc = 0; kc < 8; ++kc) {
            bf16x8 bf = *(const bf16x8*)(wrow + kc * 32 + quad * 8);
            acc = __builtin_amdgcn_mfma_f32_16x16x32_bf16(af[kc], bf, acc, 0, 0, 0);
        }
        float bias = bo[ecol];
        size_t base = (size_t)(mbase + quad * 4) * E_ + ecol;
#pragma unroll
        for (int r = 0; r < 4; ++r)
            out[base + (size_t)r * E_] = acc[r] + bias;
    }
}

extern "C" void kernel_launch(void* const* d_in, const int* in_sizes, int n_in,
                              void* d_out, int out_size, void* d_ws, size_t ws_size,
                              hipStream_t stream) {
    const float* hs   = (const float*)d_in[0];
    const float* oq   = (const float*)d_in[1];
    const float* mask = (const float*)d_in[2];
    const float* Wq   = (const float*)d_in[3];
    const float* bq   = (const float*)d_in[4];
    const float* Wk   = (const float*)d_in[5];
    const float* bk   = (const float*)d_in[6];
    const float* Wv   = (const float*)d_in[7];
    const float* bv   = (const float*)d_in[8];
    const float* Wo   = (const float*)d_in[9];
    const float* bo   = (const float*)d_in[10];
    float* out = (float*)d_out;

    const size_t nBHTD = (size_t)B_ * H_ * T_ * DH_;   // 4,194,304 elems
    unsigned short* Qw    = (unsigned short*)d_ws;
    unsigned short* Kw    = Qw + nBHTD;
    unsigned short* Vtw   = Kw + nBHTD;
    unsigned short* attnw = Vtw + nBHTD;               // 4 x 8 MB
    unsigned short* Wpack = attnw + nBHTD;             // + 512 KB
    int* mask_nz = (int*)(Wpack + 4 * 65536);

    hipMemsetAsync(mask_nz, 0, sizeof(int), stream);
    prep_maskchk_kernel<<<2048, 256, 0, stream>>>(Wq, Wk, Wv, Wo, Wpack,
                                                  (const int*)mask, mask_nz);
    qkv_kernel<<<3 * 512, 256, 0, stream>>>(hs, oq, Wpack, bq, bk, bv, Qw, Kw, Vtw);
    attn_kernel<<<B_ * H_ * (T_ / 128), 256, 0, stream>>>(Qw, Kw, Vtw, mask, mask_nz, attnw);
    oproj_kernel<<<(B_ * T_) / 16, 256, 0, stream>>>(attnw, Wpack + 3 * 65536, bo, out);
}

// Round 7
// 364.200 us; speedup vs baseline: 1.5359x; 1.0451x over previous
//
#include <hip/hip_runtime.h>

#define B_ 8
#define T_ 2048
#define E_ 256
#define H_ 8
#define DH_ 32
#define SCALING_ 0.17677669529663687f   // 1/sqrt(32)
#define LOG2E_ 1.4426950408889634f
// Q is pre-scaled by SCALING*log2(e): scores exit QK in log2 domain -> hw exp2
#define QSCALE_ (SCALING_ * LOG2E_)

typedef short bf16x8 __attribute__((ext_vector_type(8)));   // 8 bf16 in 4 VGPRs
typedef float floatx4 __attribute__((ext_vector_type(4)));

__device__ __forceinline__ unsigned short f2bf(float f) {
    union { float f; unsigned u; } v; v.f = f;
    unsigned r = v.u + 0x7FFFu + ((v.u >> 16) & 1u);   // RNE
    return (unsigned short)(r >> 16);
}

// pack 2 f32 -> 2 bf16 (round-half-up) in 3 VALU: add, add, v_perm_b32
__device__ __forceinline__ unsigned pk2(float a, float b) {
    union { float f; unsigned u; } ua, ub;
    ua.f = a; ub.f = b;
    return __builtin_amdgcn_perm(ub.u + 0x8000u, ua.u + 0x8000u, 0x07060302u);
}

__device__ __forceinline__ float fexp2(float x) {
#if __has_builtin(__builtin_amdgcn_exp2f)
    return __builtin_amdgcn_exp2f(x);
#else
    return exp2f(x);
#endif
}

__device__ __forceinline__ bf16x8 pack8(float4 a, float4 b) {
    bf16x8 o;
    o[0] = (short)f2bf(a.x); o[1] = (short)f2bf(a.y);
    o[2] = (short)f2bf(a.z); o[3] = (short)f2bf(a.w);
    o[4] = (short)f2bf(b.x); o[5] = (short)f2bf(b.y);
    o[6] = (short)f2bf(b.z); o[7] = (short)f2bf(b.w);
    return o;
}

// ---------------------------------------------------------------------------
// Kernel 0: weight prepack fp32 -> bf16 (tiny: 128 blocks).
// ---------------------------------------------------------------------------
__global__ __launch_bounds__(256) void prepack_kernel(
    const float* __restrict__ Wq, const float* __restrict__ Wk,
    const float* __restrict__ Wv, const float* __restrict__ Wo,
    unsigned short* __restrict__ Wpack) {
    int idx = blockIdx.x * 256 + threadIdx.x;   // 32768 threads
    int m = idx >> 13;                           // matrix id 0..3
    int e = (idx & 8191) * 8;
    const float* W = (m == 0) ? Wq : (m == 1) ? Wk : (m == 2) ? Wv : Wo;
    float4 a = ((const float4*)(W + e))[0];
    float4 b = ((const float4*)(W + e))[1];
    *(bf16x8*)(Wpack + (size_t)m * 65536 + e) = pack8(a, b);
}

// ---------------------------------------------------------------------------
// Kernel 1: QKV projection (blocks 0..1535) FUSED with mask nonzero check
// (blocks 1536..3583) — the 128 MB mask scan overlaps the GEMM instead of
// serializing. mask_nz pre-zeroed by hipMemsetAsync; -0.0 -> slow path.
// ---------------------------------------------------------------------------
__global__ __launch_bounds__(256, 4) void qkvmask_kernel(
    const float* __restrict__ hs, const float* __restrict__ oq,
    const unsigned short* __restrict__ Wpack,
    const float* __restrict__ bq, const float* __restrict__ bk,
    const float* __restrict__ bv,
    unsigned short* __restrict__ Qw, unsigned short* __restrict__ Kw,
    unsigned short* __restrict__ Vtw,
    const int* __restrict__ mask, int* __restrict__ mask_nz) {
    if (blockIdx.x >= 1536) {
        // ---- mask scan: 2048 blocks, grid-stride int4 OR ----
        const size_t n4 = (size_t)B_ * T_ * T_ / 4;   // 8,388,608 int4
        size_t gid = (size_t)(blockIdx.x - 1536) * 256 + threadIdx.x;
        int acc = 0;
        for (size_t i = gid; i < n4; i += (size_t)2048 * 256) {
            int4 v = ((const int4*)mask)[i];
            acc |= v.x | v.y | v.z | v.w;
        }
        if (__builtin_amdgcn_ballot_w64(acc != 0)) {
            if ((threadIdx.x & 63) == 0) atomicOr(mask_nz, 1);
        }
        return;
    }
    __shared__ __align__(16) unsigned short sX[32][264];
    const int mat = blockIdx.x >> 9;          // 0=Q, 1=K, 2=V
    const int mbase = (blockIdx.x & 511) * 32;
    const int b = mbase >> 11, tbase = mbase & 2047;
    const int tid = threadIdx.x;

#pragma unroll
    for (int i = 0; i < 8; ++i) {
        int idx = tid + i * 256;
        int row = idx >> 6, c4 = idx & 63;
        float4 hv = ((const float4*)(hs + (size_t)(mbase + row) * E_))[c4];
        if (mat < 2) {
            float4 ov = ((const float4*)(oq + (size_t)(mbase + row) * E_))[c4];
            hv.x += ov.x; hv.y += ov.y; hv.z += ov.z; hv.w += ov.w;
        }
        ushort4 pb;
        pb.x = f2bf(hv.x); pb.y = f2bf(hv.y); pb.z = f2bf(hv.z); pb.w = f2bf(hv.w);
        *(ushort4*)&sX[row][c4 * 4] = pb;
    }
    __syncthreads();

    const int wave = tid >> 6, lane = tid & 63;
    const int quad = lane >> 4, m16 = lane & 15;
    const unsigned short* W = Wpack + (size_t)mat * 65536;

    bf16x8 xf[2][8];
#pragma unroll
    for (int hgrp = 0; hgrp < 2; ++hgrp)
#pragma unroll
        for (int kc = 0; kc < 8; ++kc)
            xf[hgrp][kc] = *(const bf16x8*)&sX[hgrp * 16 + m16][kc * 32 + quad * 8];

    if (mat < 2) {
        const float* bias = (mat == 0) ? bq : bk;
        unsigned short* Out = (mat == 0) ? Qw : Kw;
#pragma unroll
        for (int i = 0; i < 4; ++i) {
            int nt = wave * 4 + i;
            int ecol = nt * 16 + m16;
            const unsigned short* wrow = W + (size_t)ecol * E_;
            floatx4 acc0 = {0.f, 0.f, 0.f, 0.f};
            floatx4 acc1 = {0.f, 0.f, 0.f, 0.f};
#pragma unroll
            for (int kc = 0; kc < 8; ++kc) {
                bf16x8 bf = *(const bf16x8*)(wrow + kc * 32 + quad * 8);
                acc0 = __builtin_amdgcn_mfma_f32_16x16x32_bf16(xf[0][kc], bf, acc0, 0, 0, 0);
                acc1 = __builtin_amdgcn_mfma_f32_16x16x32_bf16(xf[1][kc], bf, acc1, 0, 0, 0);
            }
            float bs = bias[ecol];
            int h = ecol >> 5, dh = ecol & 31;
            size_t base0 = (((size_t)b * H_ + h) * T_ + (tbase + quad * 4)) * DH_ + dh;
            size_t base1 = base0 + (size_t)16 * DH_;
#pragma unroll
            for (int r = 0; r < 4; ++r) {
                float v0 = acc0[r] + bs, v1 = acc1[r] + bs;
                if (mat == 0) { v0 *= QSCALE_; v1 *= QSCALE_; }
                Out[base0 + (size_t)r * DH_] = f2bf(v0);
                Out[base1 + (size_t)r * DH_] = f2bf(v1);
            }
        }
    } else {
#pragma unroll
        for (int i = 0; i < 4; ++i) {
            int et = wave * 4 + i;
            int erow = et * 16 + m16;
            const unsigned short* wrow = W + (size_t)erow * E_;
            floatx4 acc0 = {0.f, 0.f, 0.f, 0.f};
            floatx4 acc1 = {0.f, 0.f, 0.f, 0.f};
#pragma unroll
            for (int kc = 0; kc < 8; ++kc) {
                bf16x8 wf = *(const bf16x8*)(wrow + kc * 32 + quad * 8);
                acc0 = __builtin_amdgcn_mfma_f32_16x16x32_bf16(wf, xf[0][kc], acc0, 0, 0, 0);
                acc1 = __builtin_amdgcn_mfma_f32_16x16x32_bf16(wf, xf[1][kc], acc1, 0, 0, 0);
            }
            int t0 = tbase + m16, t1 = t0 + 16;
#pragma unroll
            for (int r = 0; r < 4; ++r) {
                int ev = et * 16 + quad * 4 + r;
                int h = ev >> 5, dh = ev & 31;
                size_t vb = (((size_t)b * H_ + h) * DH_ + dh) * T_;
                Vtw[vb + t0] = f2bf(acc0[r] + bv[ev]);
                Vtw[vb + t1] = f2bf(acc1[r] + bv[ev]);
            }
        }
    }
}

// ---------------------------------------------------------------------------
// Kernel 2: flash attention, S^T form, two q-streams per wave (R6) +
//  - scores in log2 domain (Q pre-scaled) -> raw hw exp2, no mul
//  - l computed by ones-A MFMA (1^T·P on the idle MFMA pipe); no VALU adds,
//    no end shuffles, and O/l both derive from the same bf16 P
//  - P pack via v_perm (3 VALU/pair)
//  - sPT XOR-swizzled on (m16&8) 32-short granule -> write conflicts dead
// No barriers (sPT per-wave). Grid = B*H*(T/128) = 1024 blocks.
// ---------------------------------------------------------------------------
__global__ __launch_bounds__(256, 3) void attn_kernel(
    const unsigned short* __restrict__ Qw, const unsigned short* __restrict__ Kw,
    const unsigned short* __restrict__ Vtw, const float* __restrict__ mask,
    const int* __restrict__ mask_nz, unsigned short* __restrict__ attnw) {
    __shared__ __align__(16) unsigned short sPT[4][2][16][136];  // [wave][stream][q][key^swz]
    const int tid = threadIdx.x;
    const int wave = tid >> 6, lane = tid & 63;
    const int quad = lane >> 4, m16 = lane & 15;
    const int swz = (m16 & 8) * 4;            // 0 or 32 shorts (64 B granule)
    const int bh = blockIdx.x & 63, qt = blockIdx.x >> 6;   // bh%8==h -> XCD
    const int b = bh >> 3, h = bh & 7;
    const int qA = qt * 128 + wave * 32;
    const int qB = qA + 16;
    const int mnz = *mask_nz;

    bf16x8 qfragA = *(const bf16x8*)(Qw + ((size_t)bh * T_ + qA + m16) * DH_ + quad * 8);
    bf16x8 qfragB = *(const bf16x8*)(Qw + ((size_t)bh * T_ + qB + m16) * DH_ + quad * 8);
    const unsigned short* Kb = Kw + (size_t)bh * T_ * DH_;
    const unsigned short* Vb = Vtw + (size_t)bh * DH_ * T_;
    const float* MbA = mask + ((size_t)b * T_ + qA + m16) * T_ + quad * 4;
    const float* MbB = MbA + (size_t)16 * T_;

    floatx4 O0A = {0.f, 0.f, 0.f, 0.f}, O1A = {0.f, 0.f, 0.f, 0.f};
    floatx4 O0B = {0.f, 0.f, 0.f, 0.f}, O1B = {0.f, 0.f, 0.f, 0.f};
    floatx4 LA  = {0.f, 0.f, 0.f, 0.f}, LB  = {0.f, 0.f, 0.f, 0.f};  // l accumulators
    float mprevA = -1e30f, mprevB = -1e30f;
    const floatx4 zero = {0.f, 0.f, 0.f, 0.f};

    bf16x8 ones8;
#pragma unroll
    for (int i = 0; i < 8; ++i) ones8[i] = (short)0x3F80;   // bf16 1.0

    bf16x8 kf[8];
#pragma unroll
    for (int c = 0; c < 8; ++c)
        kf[c] = *(const bf16x8*)(Kb + (size_t)(c * 16 + m16) * DH_ + quad * 8);

    for (int kt = 0; kt < 16; ++kt) {
        const int s0 = kt * 128;
#pragma unroll
        for (int hf = 0; hf < 2; ++hf) {
            const int cb = hf * 4;
            floatx4 scA[4], scB[4];
#pragma unroll
            for (int c = 0; c < 4; ++c) {
                scA[c] = __builtin_amdgcn_mfma_f32_16x16x32_bf16(kf[cb + c], qfragA, zero, 0, 0, 0);
                scB[c] = __builtin_amdgcn_mfma_f32_16x16x32_bf16(kf[cb + c], qfragB, zero, 0, 0, 0);
            }
            if (kt < 15) {
#pragma unroll
                for (int c = 0; c < 4; ++c)
                    kf[cb + c] = *(const bf16x8*)(
                        Kb + (size_t)(s0 + 128 + (cb + c) * 16 + m16) * DH_ + quad * 8);
            }
            if (!mnz) {
                // FAST PATH: raw exp2, pack, LDS. No stats, no adds.
#pragma unroll
                for (int c = 0; c < 4; ++c) {
                    float a0 = fexp2(scA[c][0]), a1 = fexp2(scA[c][1]);
                    float a2 = fexp2(scA[c][2]), a3 = fexp2(scA[c][3]);
                    float b0 = fexp2(scB[c][0]), b1 = fexp2(scB[c][1]);
                    float b2 = fexp2(scB[c][2]), b3 = fexp2(scB[c][3]);
                    uint2 wa = {pk2(a0, a1), pk2(a2, a3)};
                    uint2 wb = {pk2(b0, b1), pk2(b2, b3)};
                    int col = (((cb + c) * 16) ^ swz) + quad * 4;
                    *(uint2*)&sPT[wave][0][m16][col] = wa;
                    *(uint2*)&sPT[wave][1][m16][col] = wb;
                }
            } else {
                // SLOW PATH: online softmax in log2 domain; mask scaled by log2e.
#pragma unroll
                for (int c = 0; c < 4; ++c) {
                    float4 ma = *(const float4*)(MbA + s0 + (cb + c) * 16);
                    float4 mb = *(const float4*)(MbB + s0 + (cb + c) * 16);
                    scA[c][0] += ma.x * LOG2E_; scA[c][1] += ma.y * LOG2E_;
                    scA[c][2] += ma.z * LOG2E_; scA[c][3] += ma.w * LOG2E_;
                    scB[c][0] += mb.x * LOG2E_; scB[c][1] += mb.y * LOG2E_;
                    scB[c][2] += mb.z * LOG2E_; scB[c][3] += mb.w * LOG2E_;
                }
                float mlA = -1e30f, mlB = -1e30f;
#pragma unroll
                for (int c = 0; c < 4; ++c) {
                    mlA = fmaxf(fmaxf(fmaxf(scA[c][0], scA[c][1]), fmaxf(scA[c][2], scA[c][3])), mlA);
                    mlB = fmaxf(fmaxf(fmaxf(scB[c][0], scB[c][1]), fmaxf(scB[c][2], scB[c][3])), mlB);
                }
                mlA = fmaxf(mlA, __shfl_xor(mlA, 16, 64));
                mlA = fmaxf(mlA, __shfl_xor(mlA, 32, 64));
                mlB = fmaxf(mlB, __shfl_xor(mlB, 16, 64));
                mlB = fmaxf(mlB, __shfl_xor(mlB, 32, 64));
                float mnA = fmaxf(mprevA, mlA), mnB = fmaxf(mprevB, mlB);
                float alA = fexp2(mprevA - mnA), alB = fexp2(mprevB - mnB);
                mprevA = mnA; mprevB = mnB;
#pragma unroll
                for (int r = 0; r < 4; ++r) {
                    O0A[r] *= alA; O1A[r] *= alA; LA[r] *= alA;
                    O0B[r] *= alB; O1B[r] *= alB; LB[r] *= alB;
                }
#pragma unroll
                for (int c = 0; c < 4; ++c) {
                    float a0 = fexp2(scA[c][0] - mnA), a1 = fexp2(scA[c][1] - mnA);
                    float a2 = fexp2(scA[c][2] - mnA), a3 = fexp2(scA[c][3] - mnA);
                    float b0 = fexp2(scB[c][0] - mnB), b1 = fexp2(scB[c][1] - mnB);
                    float b2 = fexp2(scB[c][2] - mnB), b3 = fexp2(scB[c][3] - mnB);
                    uint2 wa = {pk2(a0, a1), pk2(a2, a3)};
                    uint2 wb = {pk2(b0, b1), pk2(b2, b3)};
                    int col = (((cb + c) * 16) ^ swz) + quad * 4;
                    *(uint2*)&sPT[wave][0][m16][col] = wa;
                    *(uint2*)&sPT[wave][1][m16][col] = wb;
                }
            }
        }
        // PV + l: O^T += V^T·P, L += 1^T·P (MFMA pipe), V shared by streams.
#pragma unroll
        for (int sb = 0; sb < 4; ++sb) {
            int col = ((sb * 32) ^ swz) + quad * 8;
            bf16x8 pbA = *(const bf16x8*)&sPT[wave][0][m16][col];
            bf16x8 pbB = *(const bf16x8*)&sPT[wave][1][m16][col];
            bf16x8 v0 = *(const bf16x8*)(Vb + (size_t)m16 * T_ + s0 + sb * 32 + quad * 8);
            bf16x8 v1 = *(const bf16x8*)(Vb + (size_t)(16 + m16) * T_ + s0 + sb * 32 + quad * 8);
            O0A = __builtin_amdgcn_mfma_f32_16x16x32_bf16(v0, pbA, O0A, 0, 0, 0);
            O0B = __builtin_amdgcn_mfma_f32_16x16x32_bf16(v0, pbB, O0B, 0, 0, 0);
            O1A = __builtin_amdgcn_mfma_f32_16x16x32_bf16(v1, pbA, O1A, 0, 0, 0);
            O1B = __builtin_amdgcn_mfma_f32_16x16x32_bf16(v1, pbB, O1B, 0, 0, 0);
            LA  = __builtin_amdgcn_mfma_f32_16x16x32_bf16(ones8, pbA, LA, 0, 0, 0);
            LB  = __builtin_amdgcn_mfma_f32_16x16x32_bf16(ones8, pbB, LB, 0, 0, 0);
        }
    }
    // LA/LB rows all hold l[q=m16] — no shuffles needed.
    float invA = 1.0f / LA[0], invB = 1.0f / LB[0];
    size_t obA = ((size_t)b * T_ + qA + m16) * E_ + h * DH_ + quad * 4;
    size_t obB = ((size_t)b * T_ + qB + m16) * E_ + h * DH_ + quad * 4;
    ushort4 sv;
    sv.x = f2bf(O0A[0] * invA); sv.y = f2bf(O0A[1] * invA);
    sv.z = f2bf(O0A[2] * invA); sv.w = f2bf(O0A[3] * invA);
    *(ushort4*)(attnw + obA) = sv;
    sv.x = f2bf(O1A[0] * invA); sv.y = f2bf(O1A[1] * invA);
    sv.z = f2bf(O1A[2] * invA); sv.w = f2bf(O1A[3] * invA);
    *(ushort4*)(attnw + obA + 16) = sv;
    sv.x = f2bf(O0B[0] * invB); sv.y = f2bf(O0B[1] * invB);
    sv.z = f2bf(O0B[2] * invB); sv.w = f2bf(O0B[3] * invB);
    *(ushort4*)(attnw + obB) = sv;
    sv.x = f2bf(O1B[0] * invB); sv.y = f2bf(O1B[1] * invB);
    sv.z = f2bf(O1B[2] * invB); sv.w = f2bf(O1B[3] * invB);
    *(ushort4*)(attnw + obB + 16) = sv;
}

// ---------------------------------------------------------------------------
// Kernel 3: output projection: out = attn @ Wo^T + bo  (fp32 out, bf16 weights)
// ---------------------------------------------------------------------------
__global__ __launch_bounds__(256, 4) void oproj_kernel(
    const unsigned short* __restrict__ attnw, const unsigned short* __restrict__ Wob,
    const float* __restrict__ bo, float* __restrict__ out) {
    __shared__ __align__(16) unsigned short sA[16][264];
    const int tid = threadIdx.x;
    const int mbase = blockIdx.x * 16;
#pragma unroll
    for (int i = 0; i < 4; ++i) {
        int idx = tid + i * 256;
        int row = idx >> 6, c4 = idx & 63;
        const ushort4 a = ((const ushort4*)(attnw + (size_t)(mbase + row) * E_))[c4];
        *(ushort4*)&sA[row][c4 * 4] = a;
    }
    __syncthreads();
    const int wave = tid >> 6, lane = tid & 63;
    const int quad = lane >> 4, m16 = lane & 15;

    bf16x8 af[8];
#pragma unroll
    for (int kc = 0; kc < 8; ++kc)
        af[kc] = *(const bf16x8*)&sA[m16][kc * 32 + quad * 8];

#pragma unroll
    for (int i = 0; i < 4; ++i) {
        int nt = wave * 4 + i;
        int ecol = nt * 16 + m16;
        const unsigned short* wrow = Wob + (size_t)ecol * E_;
        floatx4 acc = {0.f, 0.f, 0.f, 0.f};
#pragma unroll
        for (int kc = 0; kc < 8; ++kc) {
            bf16x8 bf = *(const bf16x8*)(wrow + kc * 32 + quad * 8);
            acc = __builtin_amdgcn_mfma_f32_16x16x32_bf16(af[kc], bf, acc, 0, 0, 0);
        }
        float bias = bo[ecol];
        size_t base = (size_t)(mbase + quad * 4) * E_ + ecol;
#pragma unroll
        for (int r = 0; r < 4; ++r)
            out[base + (size_t)r * E_] = acc[r] + bias;
    }
}

extern "C" void kernel_launch(void* const* d_in, const int* in_sizes, int n_in,
                              void* d_out, int out_size, void* d_ws, size_t ws_size,
                              hipStream_t stream) {
    const float* hs   = (const float*)d_in[0];
    const float* oq   = (const float*)d_in[1];
    const float* mask = (const float*)d_in[2];
    const float* Wq   = (const float*)d_in[3];
    const float* bq   = (const float*)d_in[4];
    const float* Wk   = (const float*)d_in[5];
    const float* bk   = (const float*)d_in[6];
    const float* Wv   = (const float*)d_in[7];
    const float* bv   = (const float*)d_in[8];
    const float* Wo   = (const float*)d_in[9];
    const float* bo   = (const float*)d_in[10];
    float* out = (float*)d_out;

    const size_t nBHTD = (size_t)B_ * H_ * T_ * DH_;   // 4,194,304 elems
    unsigned short* Qw    = (unsigned short*)d_ws;
    unsigned short* Kw    = Qw + nBHTD;
    unsigned short* Vtw   = Kw + nBHTD;
    unsigned short* attnw = Vtw + nBHTD;               // 4 x 8 MB
    unsigned short* Wpack = attnw + nBHTD;             // + 512 KB
    int* mask_nz = (int*)(Wpack + 4 * 65536);

    hipMemsetAsync(mask_nz, 0, sizeof(int), stream);
    prepack_kernel<<<128, 256, 0, stream>>>(Wq, Wk, Wv, Wo, Wpack);
    qkvmask_kernel<<<1536 + 2048, 256, 0, stream>>>(
        hs, oq, Wpack, bq, bk, bv, Qw, Kw, Vtw, (const int*)mask, mask_nz);
    attn_kernel<<<B_ * H_ * (T_ / 128), 256, 0, stream>>>(Qw, Kw, Vtw, mask, mask_nz, attnw);
    oproj_kernel<<<(B_ * T_) / 16, 256, 0, stream>>>(attnw, Wpack + 3 * 65536, bo, out);
}